// Round 14
// baseline (382.163 us; speedup 1.0000x reference)
//
#include <hip/hip_runtime.h>

// SAGEConv stack on MI355X — f16 storage + f32-accumulate dot2 pipeline.
// r14: GEMM re-tiled for LDS-pipe throughput (the r6-r13 ~50µs bound):
// 128x128 block tile, 8x8 per thread -> 16 ds_read per 256 dot2 (was 8 per 64).
// W cols split {4cq, 64+4cq} => stride-16B LDS reads (2-way alias, free).
// LDS 80KB -> 2 blocks/CU (LDS-capped; VGPR growth free). W double-buffered
// chunks as r13. k-order per output unchanged => absmax stays 0.03125.

typedef _Float16 f16;
typedef __attribute__((ext_vector_type(2))) _Float16 f16x2;
typedef __attribute__((ext_vector_type(4))) _Float16 f16x4;
typedef __attribute__((ext_vector_type(8))) _Float16 f16x8;
typedef __attribute__((ext_vector_type(4))) float f32x4;

#define HID 128

static __device__ __forceinline__ float dot2(f16x2 a, f16x2 b, float c) {
#if __has_builtin(__builtin_amdgcn_fdot2)
    return __builtin_amdgcn_fdot2(a, b, c, false);
#else
    return c + (float)a[0] * (float)b[0] + (float)a[1] * (float)b[1];
#endif
}

// ---------------- CSR build ----------------

__global__ __launch_bounds__(256) void deg_kernel(const int* __restrict__ dst, int* __restrict__ deg, int E) {
    int e = blockIdx.x * 256 + threadIdx.x;
    if (e < E) atomicAdd(&deg[dst[e]], 1);
}

__global__ __launch_bounds__(256) void scan1_kernel(const int* __restrict__ deg, int* __restrict__ incl,
                                                    int* __restrict__ blksum, int N) {
    __shared__ int sm[256];
    int i = blockIdx.x * 256 + threadIdx.x;
    int v = (i < N) ? deg[i] : 0;
    sm[threadIdx.x] = v;
    __syncthreads();
    for (int d = 1; d < 256; d <<= 1) {
        int t = (threadIdx.x >= d) ? sm[threadIdx.x - d] : 0;
        __syncthreads();
        sm[threadIdx.x] += t;
        __syncthreads();
    }
    if (i < N) incl[i] = sm[threadIdx.x];
    if (threadIdx.x == 255) blksum[blockIdx.x] = sm[255];
}

__global__ __launch_bounds__(256) void scan2_kernel(const int* __restrict__ blksum, int* __restrict__ blkoff, int nb) {
    __shared__ int sm[256];
    int t = threadIdx.x;
    int v = (t < nb) ? blksum[t] : 0;
    sm[t] = v;
    __syncthreads();
    for (int d = 1; d < 256; d <<= 1) {
        int u = (t >= d) ? sm[t - d] : 0;
        __syncthreads();
        sm[t] += u;
        __syncthreads();
    }
    if (t < nb) blkoff[t] = sm[t] - v;  // exclusive
}

__global__ __launch_bounds__(256) void scan3_kernel(const int* __restrict__ incl, const int* __restrict__ deg,
                                                    const int* __restrict__ blkoff, int* __restrict__ rowptr,
                                                    int N, int E) {
    int i = blockIdx.x * 256 + threadIdx.x;
    if (i < N) rowptr[i] = incl[i] - deg[i] + blkoff[blockIdx.x];
    if (i == 0) rowptr[N] = E;
}

__global__ __launch_bounds__(256) void fill_kernel(const int* __restrict__ src, const int* __restrict__ dst,
                                                   const int* __restrict__ rowptr, int* __restrict__ cnt,
                                                   int* __restrict__ colA, int E) {
    int e = blockIdx.x * 256 + threadIdx.x;
    if (e < E) {
        int d = dst[e];
        int p = rowptr[d] + atomicAdd(&cnt[d], 1);
        colA[p] = src[e];
    }
}

// ---------------- W -> k-pair-interleaved f16 ----------------
// Wp layout: [kp][c][2] f16 — pair (W[2kp][c], W[2kp+1][c]). 32-k chunk c is
// the contiguous 8KB at Wp + c*4096 (f16 units).

__global__ __launch_bounds__(256) void wpack_kernel(const float* __restrict__ inW, const float* __restrict__ Wl,
                                                    const float* __restrict__ Wr, f16* __restrict__ Wp0,
                                                    f16* __restrict__ WpL, int nlayers) {
    int idx = blockIdx.x * 256 + threadIdx.x;
    int total = 64 * HID + nlayers * HID * HID;  // pair-slots
    if (idx >= total) return;
    if (idx < 64 * HID) {
        int kp = idx / HID, c = idx % HID;
        Wp0[idx * 2 + 0] = (f16)inW[(2 * kp) * HID + c];
        Wp0[idx * 2 + 1] = (f16)inW[(2 * kp + 1) * HID + c];
    } else {
        int r0 = idx - 64 * HID;
        int l = r0 / (HID * HID);
        int r = r0 % (HID * HID);
        int kp = r / HID, c = r % HID;
        int k0 = 2 * kp;
        const float* W = (k0 < HID) ? (Wl + (size_t)l * HID * HID + (size_t)k0 * HID)
                                    : (Wr + (size_t)l * HID * HID + (size_t)(k0 - HID) * HID);
        WpL[(size_t)r0 * 2 + 0] = (f16)W[c];
        WpL[(size_t)r0 * 2 + 1] = (f16)W[HID + c];
    }
}

// ---------------- mean aggregation: wave/node, 16 edges in flight ----------------

__global__ __launch_bounds__(256) void aggh_kernel(const f16* __restrict__ h16, const int* __restrict__ rowptr,
                                                   const int* __restrict__ colA,
                                                   f16* __restrict__ agg, int N) {
    int wid = blockIdx.x * 4 + (threadIdx.x >> 6);
    int lane = threadIdx.x & 63;
    if (wid >= N) return;
    int b = rowptr[wid], e = rowptr[wid + 1];
    int grp = lane >> 4, sub = lane & 15;
    float ax[8] = {};
    for (int j0 = b; j0 < e; j0 += 16) {
        int j1 = j0 + grp, j2 = j0 + 4 + grp, j3 = j0 + 8 + grp, j4 = j0 + 12 + grp;
        f16x8 v1 = {}, v2 = {}, v3 = {}, v4 = {};
        if (j1 < e) v1 = *(const f16x8*)(h16 + (size_t)colA[j1] * HID + sub * 8);
        if (j2 < e) v2 = *(const f16x8*)(h16 + (size_t)colA[j2] * HID + sub * 8);
        if (j3 < e) v3 = *(const f16x8*)(h16 + (size_t)colA[j3] * HID + sub * 8);
        if (j4 < e) v4 = *(const f16x8*)(h16 + (size_t)colA[j4] * HID + sub * 8);
        #pragma unroll
        for (int i = 0; i < 8; i++)
            ax[i] += ((float)v1[i] + (float)v2[i]) + ((float)v3[i] + (float)v4[i]);
    }
    #pragma unroll
    for (int i = 0; i < 8; i++) {
        ax[i] += __shfl_xor(ax[i], 16);
        ax[i] += __shfl_xor(ax[i], 32);
    }
    if (lane < 16) {
        float id = 1.0f / (float)((e - b) > 1 ? (e - b) : 1);
        f16x8 o;
        #pragma unroll
        for (int i = 0; i < 8; i++) o[i] = (f16)(ax[i] * id);
        *(f16x8*)(agg + (size_t)wid * HID + sub * 8) = o;
    }
}

// ---------------- dot2-f16 GEMM: 128x128 tile, 8x8/thread, LDS-W dbuf ----------------
// cq=tid&15 -> cols {4cq..+3, 64+4cq..+3}; rg=tid>>4 -> rows 8rg..+7.
// Per 8-k substep: 8 A-reads (16-lane broadcast, free) + 8 W-reads (stride-16B,
// 2-way alias, free) for 256 dot2 -> LDS pipe 768cy vs VALU 512cy per block
// (r13 was 1536 vs 512 -> LDS-bound at ~50µs). LDS 80KB -> 2 blocks/CU.
// #pragma unroll 1 on chunk loop (r9: unbounded unroll hoists loads -> spill).
// Row's 128 cols live in one ALIGNED 16-lane group (tid=rg*16+cq) -> shfl LN.
// In-place safety (out16==A1==resid16): blocks own disjoint 128-row sets; stage
// reads own rows pre-barrier (tail clamp in-tile); resid (row,col) read by its
// writing thread before the write.

template <int NK, bool FUSE, bool LAST>
__global__ __launch_bounds__(256) void gemmx_kernel(
    const void* __restrict__ A0v, const f16* __restrict__ A1,
    const f16* __restrict__ Wp,
    const float* __restrict__ bias, const float* __restrict__ lng, const float* __restrict__ lnb,
    const f16* resid16, f16* out16, float* out32, int N) {
    constexpr int K = NK * 32;
    __shared__ f16 a_lds[128][K];   // NK=8: 64KB, NK=4: 32KB
    __shared__ f16 w_lds[2][4096];  // 8KB per buffer: [kp 0..15][col 0..127][2]

    const int tid = threadIdx.x;
    const int cq = tid & 15;
    const int rg = tid >> 4;
    const int row0 = blockIdx.x * 128;

    // stage A rows (f16 in LDS; clamp tail rows)
    constexpr int CPR = K / 8;  // 16B chunks per row
    for (int c = tid; c < 128 * CPR; c += 256) {
        int r = c / CPR;
        int col = (c % CPR) * 8;
        int gr = row0 + r;
        if (gr >= N) gr = N - 1;
        f16x8 v;
        if constexpr (NK == 8) {
            const f16* A0 = (const f16*)A0v;
            if (col < HID) v = *(const f16x8*)(A0 + (size_t)gr * HID + col);
            else           v = *(const f16x8*)(A1 + (size_t)gr * HID + (col - HID));
        } else {
            const float* xr = (const float*)A0v + (size_t)gr * HID + col;
            f32x4 v0 = *(const f32x4*)xr;
            f32x4 v1 = *(const f32x4*)(xr + 4);
            v[0] = (f16)v0[0]; v[1] = (f16)v0[1]; v[2] = (f16)v0[2]; v[3] = (f16)v0[3];
            v[4] = (f16)v1[0]; v[5] = (f16)v1[1]; v[6] = (f16)v1[2]; v[7] = (f16)v1[3];
        }
        *(f16x8*)&a_lds[r][col] = v;
    }

    // W chunk 0 -> buf 0 (32B/thread)
    {
        f16x8 r0 = *(const f16x8*)(Wp + tid * 16);
        f16x8 r1 = *(const f16x8*)(Wp + tid * 16 + 8);
        *(f16x8*)&w_lds[0][tid * 16] = r0;
        *(f16x8*)&w_lds[0][tid * 16 + 8] = r1;
    }
    __syncthreads();

    float acc0[8][4] = {};  // cols 4cq..+3
    float acc1[8][4] = {};  // cols 64+4cq..+3
    f16x8 wr0, wr1;

    #pragma unroll 1
    for (int c = 0; c < NK; ++c) {
        // issue next chunk's global loads (latency hides under this chunk's compute)
        if (c + 1 < NK) {
            wr0 = *(const f16x8*)(Wp + (size_t)(c + 1) * 4096 + tid * 16);
            wr1 = *(const f16x8*)(Wp + (size_t)(c + 1) * 4096 + tid * 16 + 8);
        }
        const f16* wb = &w_lds[c & 1][0];
        #pragma unroll
        for (int q = 0; q < 4; ++q) {  // 4 sub-steps of 8 k
            f16x8 a[8];
            #pragma unroll
            for (int j = 0; j < 8; j++) a[j] = *(const f16x8*)&a_lds[rg * 8 + j][c * 32 + q * 8];
            #pragma unroll
            for (int p = 0; p < 4; ++p) {
                int kp = q * 4 + p;
                f16x8 w0 = *(const f16x8*)(wb + kp * 256 + cq * 8);        // cols 4cq..+3
                f16x8 w1 = *(const f16x8*)(wb + kp * 256 + 128 + cq * 8);  // cols 64+4cq..+3
                #pragma unroll
                for (int j = 0; j < 8; j++) {
                    f16x2 ap; ap[0] = a[j][2 * p]; ap[1] = a[j][2 * p + 1];
                    #pragma unroll
                    for (int cc = 0; cc < 4; cc++) {
                        f16x2 wp2; wp2[0] = w0[2 * cc]; wp2[1] = w0[2 * cc + 1];
                        acc0[j][cc] = dot2(ap, wp2, acc0[j][cc]);
                    }
                    #pragma unroll
                    for (int cc = 0; cc < 4; cc++) {
                        f16x2 wp2; wp2[0] = w1[2 * cc]; wp2[1] = w1[2 * cc + 1];
                        acc1[j][cc] = dot2(ap, wp2, acc1[j][cc]);
                    }
                }
            }
        }
        // publish next chunk into the other buffer
        if (c + 1 < NK) {
            *(f16x8*)&w_lds[(c + 1) & 1][tid * 16] = wr0;
            *(f16x8*)&w_lds[(c + 1) & 1][tid * 16 + 8] = wr1;
        }
        __syncthreads();
    }

    // epilogue
    f32x4 bv0 = *(const f32x4*)(bias + cq * 4);
    f32x4 bv1 = *(const f32x4*)(bias + 64 + cq * 4);
    f32x4 gv0 = {}, gv1 = {}, lv0 = {}, lv1 = {};
    if constexpr (FUSE) {
        gv0 = *(const f32x4*)(lng + cq * 4);
        gv1 = *(const f32x4*)(lng + 64 + cq * 4);
        lv0 = *(const f32x4*)(lnb + cq * 4);
        lv1 = *(const f32x4*)(lnb + 64 + cq * 4);
    }
    #pragma unroll
    for (int j = 0; j < 8; j++) {
        int gr = row0 + rg * 8 + j;
        int grc = (gr < N) ? gr : (N - 1);
        f32x4 z0, z1;
        #pragma unroll
        for (int c = 0; c < 4; c++) { z0[c] = acc0[j][c] + bv0[c]; z1[c] = acc1[j][c] + bv1[c]; }
        if constexpr (FUSE) {
            f16x4 r0 = *(const f16x4*)(resid16 + (size_t)grc * HID + cq * 4);
            f16x4 r1 = *(const f16x4*)(resid16 + (size_t)grc * HID + 64 + cq * 4);
            #pragma unroll
            for (int c = 0; c < 4; c++) {
                z0[c] = fmaxf(z0[c], 0.f) + (float)r0[c];
                z1[c] = fmaxf(z1[c], 0.f) + (float)r1[c];
            }
            // row LN: the row's 128 cols live in one aligned 16-lane group
            float s = z0[0] + z0[1] + z0[2] + z0[3] + z1[0] + z1[1] + z1[2] + z1[3];
            float s2 = z0[0] * z0[0] + z0[1] * z0[1] + z0[2] * z0[2] + z0[3] * z0[3]
                     + z1[0] * z1[0] + z1[1] * z1[1] + z1[2] * z1[2] + z1[3] * z1[3];
            #pragma unroll
            for (int d = 1; d < 16; d <<= 1) {
                s += __shfl_xor(s, d);
                s2 += __shfl_xor(s2, d);
            }
            float mu = s * (1.f / 128.f);
            float var = s2 * (1.f / 128.f) - mu * mu;
            float rs = rsqrtf(var + 1e-5f);
            #pragma unroll
            for (int c = 0; c < 4; c++) {
                z0[c] = (z0[c] - mu) * rs * gv0[c] + lv0[c];
                z1[c] = (z1[c] - mu) * rs * gv1[c] + lv1[c];
            }
        }
        if (gr < N) {
            if constexpr (LAST) {
                *(f32x4*)(out32 + (size_t)gr * HID + cq * 4) = z0;
                *(f32x4*)(out32 + (size_t)gr * HID + 64 + cq * 4) = z1;
            } else {
                f16x4 p0, p1;
                #pragma unroll
                for (int c = 0; c < 4; c++) { p0[c] = (f16)z0[c]; p1[c] = (f16)z1[c]; }
                *(f16x4*)(out16 + (size_t)gr * HID + cq * 4) = p0;
                *(f16x4*)(out16 + (size_t)gr * HID + 64 + cq * 4) = p1;
            }
        }
    }
}

// ---------------- launch ----------------

extern "C" void kernel_launch(void* const* d_in, const int* in_sizes, int n_in,
                              void* d_out, int out_size, void* d_ws, size_t ws_size,
                              hipStream_t stream) {
    const float* x = (const float*)d_in[0];
    const int* ei = (const int*)d_in[1];
    const float* inW = (const float*)d_in[2];
    const float* inb = (const float*)d_in[3];
    const float* Wl = (const float*)d_in[4];
    const float* bl = (const float*)d_in[5];
    const float* Wr = (const float*)d_in[6];
    const float* lng = (const float*)d_in[7];
    const float* lnb = (const float*)d_in[8];
    float* out = (float*)d_out;

    const int N = in_sizes[0] / HID;
    const int E = in_sizes[1] / 2;
    const int NL = 3;
    const int* src = ei;
    const int* dst = ei + E;

    char* w = (char*)d_ws;
    auto alloc = [&](size_t bytes) -> char* {
        char* p = w;
        w += (bytes + 255) & ~(size_t)255;
        return p;
    };
    int* degcnt = (int*)alloc((size_t)2 * N * 4);  // one alloc: single memset covers both
    int* deg = degcnt;
    int* cnt = degcnt + N;
    int* rowptr = (int*)alloc((N + 1) * 4);
    int* incl = (int*)alloc(N * 4);
    int* blksum = (int*)alloc(256 * 4);
    int* blkoff = (int*)alloc(256 * 4);
    int* colA = (int*)alloc((size_t)E * 4);
    f16* H16 = (f16*)alloc((size_t)N * HID * 2);    // f16 h (all consumers)
    f16* AGG16 = (f16*)alloc((size_t)N * HID * 2);  // f16 aggregate
    f16* Wp0 = (f16*)alloc((size_t)64 * HID * 2 * 2);
    f16* WpL = (f16*)alloc((size_t)NL * HID * HID * 2 * 2);

    const int nbN = (N + 255) / 256;
    const int nbE = (E + 255) / 256;

    hipMemsetAsync(degcnt, 0, (size_t)2 * N * 4, stream);

    deg_kernel<<<nbE, 256, 0, stream>>>(dst, deg, E);
    scan1_kernel<<<nbN, 256, 0, stream>>>(deg, incl, blksum, N);
    scan2_kernel<<<1, 256, 0, stream>>>(blksum, blkoff, nbN);
    scan3_kernel<<<nbN, 256, 0, stream>>>(incl, deg, blkoff, rowptr, N, E);
    fill_kernel<<<nbE, 256, 0, stream>>>(src, dst, rowptr, cnt, colA, E);
    // no sort: agg f32 sum order varies ~1e-6; validation is threshold-based

    const int wslots = 64 * HID + NL * HID * HID;
    wpack_kernel<<<(wslots + 255) / 256, 256, 0, stream>>>(inW, Wl, Wr, Wp0, WpL, NL);

    const int gb = (N + 127) / 128;
    const int aggblocks = (N + 3) / 4;

    // input projection: h = x @ in_W + in_b  -> H16 (x converted during stage)
    gemmx_kernel<4, false, false><<<gb, 256, 0, stream>>>(
        x, nullptr, Wp0, inb, nullptr, nullptr, nullptr, H16, nullptr, N);

    for (int i = 0; i < NL; i++) {
        aggh_kernel<<<aggblocks, 256, 0, stream>>>(H16, rowptr, colA, AGG16, N);
        const f16* wpi = WpL + (size_t)i * HID * HID * 2;
        if (i == NL - 1) {
            gemmx_kernel<8, true, true><<<gb, 256, 0, stream>>>(
                AGG16, H16, wpi, bl + i * HID, lng + i * HID, lnb + i * HID,
                H16, nullptr, out, N);
        } else {
            // in-place h update (own-rows-only reads precede writes)
            gemmx_kernel<8, true, false><<<gb, 256, 0, stream>>>(
                AGG16, H16, wpi, bl + i * HID, lng + i * HID, lnb + i * HID,
                H16, H16, nullptr, N);
        }
    }
}

// Round 17
// 307.528 us; speedup vs baseline: 1.2427x; 1.2427x over previous
//
#include <hip/hip_runtime.h>

// SAGEConv stack on MI355X — f16 storage + f32-accumulate dot2 pipeline (r10 base).
// r17 = r13 VERBATIM (best passing: 309.7µs, absmax 0.03125). r15/r16's
// micro-edits (bit_cast operands + staging remap) both failed correctness in
// ways static analysis could not localize — reverted per last-known-good rule.
// W staged in LDS per 32-k chunk, double-buffered (one barrier/chunk).

typedef _Float16 f16;
typedef __attribute__((ext_vector_type(2))) _Float16 f16x2;
typedef __attribute__((ext_vector_type(4))) _Float16 f16x4;
typedef __attribute__((ext_vector_type(8))) _Float16 f16x8;
typedef __attribute__((ext_vector_type(4))) float f32x4;

#define HID 128

static __device__ __forceinline__ float dot2(f16x2 a, f16x2 b, float c) {
#if __has_builtin(__builtin_amdgcn_fdot2)
    return __builtin_amdgcn_fdot2(a, b, c, false);
#else
    return c + (float)a[0] * (float)b[0] + (float)a[1] * (float)b[1];
#endif
}

// ---------------- CSR build ----------------

__global__ __launch_bounds__(256) void deg_kernel(const int* __restrict__ dst, int* __restrict__ deg, int E) {
    int e = blockIdx.x * 256 + threadIdx.x;
    if (e < E) atomicAdd(&deg[dst[e]], 1);
}

__global__ __launch_bounds__(256) void scan1_kernel(const int* __restrict__ deg, int* __restrict__ incl,
                                                    int* __restrict__ blksum, int N) {
    __shared__ int sm[256];
    int i = blockIdx.x * 256 + threadIdx.x;
    int v = (i < N) ? deg[i] : 0;
    sm[threadIdx.x] = v;
    __syncthreads();
    for (int d = 1; d < 256; d <<= 1) {
        int t = (threadIdx.x >= d) ? sm[threadIdx.x - d] : 0;
        __syncthreads();
        sm[threadIdx.x] += t;
        __syncthreads();
    }
    if (i < N) incl[i] = sm[threadIdx.x];
    if (threadIdx.x == 255) blksum[blockIdx.x] = sm[255];
}

__global__ __launch_bounds__(256) void scan2_kernel(const int* __restrict__ blksum, int* __restrict__ blkoff, int nb) {
    __shared__ int sm[256];
    int t = threadIdx.x;
    int v = (t < nb) ? blksum[t] : 0;
    sm[t] = v;
    __syncthreads();
    for (int d = 1; d < 256; d <<= 1) {
        int u = (t >= d) ? sm[t - d] : 0;
        __syncthreads();
        sm[t] += u;
        __syncthreads();
    }
    if (t < nb) blkoff[t] = sm[t] - v;  // exclusive
}

__global__ __launch_bounds__(256) void scan3_kernel(const int* __restrict__ incl, const int* __restrict__ deg,
                                                    const int* __restrict__ blkoff, int* __restrict__ rowptr,
                                                    int N, int E) {
    int i = blockIdx.x * 256 + threadIdx.x;
    if (i < N) rowptr[i] = incl[i] - deg[i] + blkoff[blockIdx.x];
    if (i == 0) rowptr[N] = E;
}

__global__ __launch_bounds__(256) void fill_kernel(const int* __restrict__ src, const int* __restrict__ dst,
                                                   const int* __restrict__ rowptr, int* __restrict__ cnt,
                                                   int* __restrict__ colA, int E) {
    int e = blockIdx.x * 256 + threadIdx.x;
    if (e < E) {
        int d = dst[e];
        int p = rowptr[d] + atomicAdd(&cnt[d], 1);
        colA[p] = src[e];
    }
}

// ---------------- W -> k-pair-interleaved f16 ----------------
// Wp layout: [kp][c][2] f16 — pair (W[2kp][c], W[2kp+1][c]). 32-k chunk c is
// the contiguous 8KB at Wp + c*4096 (f16 units).

__global__ __launch_bounds__(256) void wpack_kernel(const float* __restrict__ inW, const float* __restrict__ Wl,
                                                    const float* __restrict__ Wr, f16* __restrict__ Wp0,
                                                    f16* __restrict__ WpL, int nlayers) {
    int idx = blockIdx.x * 256 + threadIdx.x;
    int total = 64 * HID + nlayers * HID * HID;  // pair-slots
    if (idx >= total) return;
    if (idx < 64 * HID) {
        int kp = idx / HID, c = idx % HID;
        Wp0[idx * 2 + 0] = (f16)inW[(2 * kp) * HID + c];
        Wp0[idx * 2 + 1] = (f16)inW[(2 * kp + 1) * HID + c];
    } else {
        int r0 = idx - 64 * HID;
        int l = r0 / (HID * HID);
        int r = r0 % (HID * HID);
        int kp = r / HID, c = r % HID;
        int k0 = 2 * kp;
        const float* W = (k0 < HID) ? (Wl + (size_t)l * HID * HID + (size_t)k0 * HID)
                                    : (Wr + (size_t)l * HID * HID + (size_t)(k0 - HID) * HID);
        WpL[(size_t)r0 * 2 + 0] = (f16)W[c];
        WpL[(size_t)r0 * 2 + 1] = (f16)W[HID + c];
    }
}

// ---------------- mean aggregation: wave/node, 16 edges in flight ----------------

__global__ __launch_bounds__(256) void aggh_kernel(const f16* __restrict__ h16, const int* __restrict__ rowptr,
                                                   const int* __restrict__ colA,
                                                   f16* __restrict__ agg, int N) {
    int wid = blockIdx.x * 4 + (threadIdx.x >> 6);
    int lane = threadIdx.x & 63;
    if (wid >= N) return;
    int b = rowptr[wid], e = rowptr[wid + 1];
    int grp = lane >> 4, sub = lane & 15;
    float ax[8] = {};
    for (int j0 = b; j0 < e; j0 += 16) {
        int j1 = j0 + grp, j2 = j0 + 4 + grp, j3 = j0 + 8 + grp, j4 = j0 + 12 + grp;
        f16x8 v1 = {}, v2 = {}, v3 = {}, v4 = {};
        if (j1 < e) v1 = *(const f16x8*)(h16 + (size_t)colA[j1] * HID + sub * 8);
        if (j2 < e) v2 = *(const f16x8*)(h16 + (size_t)colA[j2] * HID + sub * 8);
        if (j3 < e) v3 = *(const f16x8*)(h16 + (size_t)colA[j3] * HID + sub * 8);
        if (j4 < e) v4 = *(const f16x8*)(h16 + (size_t)colA[j4] * HID + sub * 8);
        #pragma unroll
        for (int i = 0; i < 8; i++)
            ax[i] += ((float)v1[i] + (float)v2[i]) + ((float)v3[i] + (float)v4[i]);
    }
    #pragma unroll
    for (int i = 0; i < 8; i++) {
        ax[i] += __shfl_xor(ax[i], 16);
        ax[i] += __shfl_xor(ax[i], 32);
    }
    if (lane < 16) {
        float id = 1.0f / (float)((e - b) > 1 ? (e - b) : 1);
        f16x8 o;
        #pragma unroll
        for (int i = 0; i < 8; i++) o[i] = (f16)(ax[i] * id);
        *(f16x8*)(agg + (size_t)wid * HID + sub * 8) = o;
    }
}

// ---------------- dot2-f16 GEMM with LDS-staged W (double-buffered chunks) ----------------
// Block: 256 thr, 32 rows x 128 cols, 4x4/thread (cq=tid&31 cols, rg=tid>>5 rows).
// Per 32-k chunk: cooperative 8KB W load (32B/thread: global->reg at top of iter,
// ds_write at bottom, ONE barrier). W reads and A reads from LDS are half-wave
// broadcasts. #pragma unroll 1 on chunk loop (r9: unbounded unroll hoists
// global loads -> spill).
// In-place safety (out16==A1==resid16): blocks own disjoint 32-row sets; stage
// reads own rows pre-barrier; resid (row,col) read by its writing thread pre-write.

template <int NK, bool FUSE, bool LAST>
__global__ __launch_bounds__(256) void gemmw_kernel(
    const void* __restrict__ A0v, const f16* __restrict__ A1,
    const f16* __restrict__ Wp,
    const float* __restrict__ bias, const float* __restrict__ lng, const float* __restrict__ lnb,
    const f16* resid16, f16* out16, float* out32, int N) {
    constexpr int K = NK * 32;
    __shared__ f16 a_lds[32][K];
    __shared__ f16 w_lds[2][4096];  // 8KB per buffer: [kp 0..15][col 0..127][2]

    const int tid = threadIdx.x;
    const int cq = tid & 31;
    const int rg = tid >> 5;
    const int row0 = blockIdx.x * 32;

    // stage A rows (f16 in LDS; clamp tail rows)
    constexpr int CPR = K / 8;  // 16B chunks per row
    for (int c = tid; c < 32 * CPR; c += 256) {
        int r = c / CPR;
        int col = (c % CPR) * 8;
        int gr = row0 + r;
        if (gr >= N) gr = N - 1;
        f16x8 v;
        if constexpr (NK == 8) {
            const f16* A0 = (const f16*)A0v;
            if (col < HID) v = *(const f16x8*)(A0 + (size_t)gr * HID + col);
            else           v = *(const f16x8*)(A1 + (size_t)gr * HID + (col - HID));
        } else {
            const float* xr = (const float*)A0v + (size_t)gr * HID + col;
            f32x4 v0 = *(const f32x4*)xr;
            f32x4 v1 = *(const f32x4*)(xr + 4);
            v[0] = (f16)v0[0]; v[1] = (f16)v0[1]; v[2] = (f16)v0[2]; v[3] = (f16)v0[3];
            v[4] = (f16)v1[0]; v[5] = (f16)v1[1]; v[6] = (f16)v1[2]; v[7] = (f16)v1[3];
        }
        *(f16x8*)&a_lds[r][col] = v;
    }

    // W chunk 0 -> buf 0 (32B/thread)
    {
        f16x8 r0 = *(const f16x8*)(Wp + tid * 16);
        f16x8 r1 = *(const f16x8*)(Wp + tid * 16 + 8);
        *(f16x8*)&w_lds[0][tid * 16] = r0;
        *(f16x8*)&w_lds[0][tid * 16 + 8] = r1;
    }
    __syncthreads();

    float acc[4][4] = {};
    f16x8 wr0, wr1;

    #pragma unroll 1
    for (int c = 0; c < NK; ++c) {
        // issue next chunk's global loads (latency hides under this chunk's compute)
        if (c + 1 < NK) {
            wr0 = *(const f16x8*)(Wp + (size_t)(c + 1) * 4096 + tid * 16);
            wr1 = *(const f16x8*)(Wp + (size_t)(c + 1) * 4096 + tid * 16 + 8);
        }
        const f16* wb = &w_lds[c & 1][0];
        #pragma unroll
        for (int q = 0; q < 4; ++q) {  // 4 sub-steps of 8 k
            f16x8 a[4];
            #pragma unroll
            for (int j = 0; j < 4; j++) a[j] = *(const f16x8*)&a_lds[rg * 4 + j][c * 32 + q * 8];
            #pragma unroll
            for (int p = 0; p < 4; ++p) {
                int kp = q * 4 + p;
                f16x8 w = *(const f16x8*)(wb + kp * 256 + cq * 8);
                #pragma unroll
                for (int j = 0; j < 4; j++) {
                    f16x2 ap; ap[0] = a[j][2 * p]; ap[1] = a[j][2 * p + 1];
                    #pragma unroll
                    for (int cc = 0; cc < 4; cc++) {
                        f16x2 wp2; wp2[0] = w[2 * cc]; wp2[1] = w[2 * cc + 1];
                        acc[j][cc] = dot2(ap, wp2, acc[j][cc]);
                    }
                }
            }
        }
        // publish next chunk into the other buffer (distinct from the one just read)
        if (c + 1 < NK) {
            *(f16x8*)&w_lds[(c + 1) & 1][tid * 16] = wr0;
            *(f16x8*)&w_lds[(c + 1) & 1][tid * 16 + 8] = wr1;
        }
        __syncthreads();
    }

    // epilogue
    f32x4 bv = *(const f32x4*)(bias + cq * 4);
    f32x4 gv = {}, lv = {};
    if constexpr (FUSE) {
        gv = *(const f32x4*)(lng + cq * 4);
        lv = *(const f32x4*)(lnb + cq * 4);
    }
    #pragma unroll
    for (int j = 0; j < 4; j++) {
        int gr = row0 + rg * 4 + j;
        int grc = (gr < N) ? gr : (N - 1);
        f32x4 z;
        #pragma unroll
        for (int c = 0; c < 4; c++) z[c] = acc[j][c] + bv[c];
        if constexpr (FUSE) {
            f16x4 res = *(const f16x4*)(resid16 + (size_t)grc * HID + cq * 4);
            #pragma unroll
            for (int c = 0; c < 4; c++) z[c] = fmaxf(z[c], 0.f) + (float)res[c];
            // row LN within the aligned 32-lane group (rg constant across it)
            float s = z[0] + z[1] + z[2] + z[3];
            float s2 = z[0] * z[0] + z[1] * z[1] + z[2] * z[2] + z[3] * z[3];
            #pragma unroll
            for (int d = 1; d < 32; d <<= 1) {
                s += __shfl_xor(s, d);
                s2 += __shfl_xor(s2, d);
            }
            float mu = s * (1.f / 128.f);
            float var = s2 * (1.f / 128.f) - mu * mu;
            float rs = rsqrtf(var + 1e-5f);
            #pragma unroll
            for (int c = 0; c < 4; c++) z[c] = (z[c] - mu) * rs * gv[c] + lv[c];
        }
        if (gr < N) {
            if constexpr (LAST) {
                *(f32x4*)(out32 + (size_t)gr * HID + cq * 4) = z;
            } else {
                f16x4 p;
                #pragma unroll
                for (int c = 0; c < 4; c++) p[c] = (f16)z[c];
                *(f16x4*)(out16 + (size_t)gr * HID + cq * 4) = p;
            }
        }
    }
}

// ---------------- launch ----------------

extern "C" void kernel_launch(void* const* d_in, const int* in_sizes, int n_in,
                              void* d_out, int out_size, void* d_ws, size_t ws_size,
                              hipStream_t stream) {
    const float* x = (const float*)d_in[0];
    const int* ei = (const int*)d_in[1];
    const float* inW = (const float*)d_in[2];
    const float* inb = (const float*)d_in[3];
    const float* Wl = (const float*)d_in[4];
    const float* bl = (const float*)d_in[5];
    const float* Wr = (const float*)d_in[6];
    const float* lng = (const float*)d_in[7];
    const float* lnb = (const float*)d_in[8];
    float* out = (float*)d_out;

    const int N = in_sizes[0] / HID;
    const int E = in_sizes[1] / 2;
    const int NL = 3;
    const int* src = ei;
    const int* dst = ei + E;

    char* w = (char*)d_ws;
    auto alloc = [&](size_t bytes) -> char* {
        char* p = w;
        w += (bytes + 255) & ~(size_t)255;
        return p;
    };
    int* degcnt = (int*)alloc((size_t)2 * N * 4);  // one alloc: single memset covers both
    int* deg = degcnt;
    int* cnt = degcnt + N;
    int* rowptr = (int*)alloc((N + 1) * 4);
    int* incl = (int*)alloc(N * 4);
    int* blksum = (int*)alloc(256 * 4);
    int* blkoff = (int*)alloc(256 * 4);
    int* colA = (int*)alloc((size_t)E * 4);
    f16* H16 = (f16*)alloc((size_t)N * HID * 2);    // f16 h (all consumers)
    f16* AGG16 = (f16*)alloc((size_t)N * HID * 2);  // f16 aggregate
    f16* Wp0 = (f16*)alloc((size_t)64 * HID * 2 * 2);
    f16* WpL = (f16*)alloc((size_t)NL * HID * HID * 2 * 2);

    const int nbN = (N + 255) / 256;
    const int nbE = (E + 255) / 256;

    hipMemsetAsync(degcnt, 0, (size_t)2 * N * 4, stream);

    deg_kernel<<<nbE, 256, 0, stream>>>(dst, deg, E);
    scan1_kernel<<<nbN, 256, 0, stream>>>(deg, incl, blksum, N);
    scan2_kernel<<<1, 256, 0, stream>>>(blksum, blkoff, nbN);
    scan3_kernel<<<nbN, 256, 0, stream>>>(incl, deg, blkoff, rowptr, N, E);
    fill_kernel<<<nbE, 256, 0, stream>>>(src, dst, rowptr, cnt, colA, E);
    // no sort: agg f32 sum order varies ~1e-6; validation is threshold-based

    const int wslots = 64 * HID + NL * HID * HID;
    wpack_kernel<<<(wslots + 255) / 256, 256, 0, stream>>>(inW, Wl, Wr, Wp0, WpL, NL);

    const int gb = (N + 31) / 32;
    const int aggblocks = (N + 3) / 4;

    // input projection: h = x @ in_W + in_b  -> H16 (x converted during stage)
    gemmw_kernel<4, false, false><<<gb, 256, 0, stream>>>(
        x, nullptr, Wp0, inb, nullptr, nullptr, nullptr, H16, nullptr, N);

    for (int i = 0; i < NL; i++) {
        aggh_kernel<<<aggblocks, 256, 0, stream>>>(H16, rowptr, colA, AGG16, N);
        const f16* wpi = WpL + (size_t)i * HID * HID * 2;
        if (i == NL - 1) {
            gemmw_kernel<8, true, true><<<gb, 256, 0, stream>>>(
                AGG16, H16, wpi, bl + i * HID, lng + i * HID, lnb + i * HID,
                H16, nullptr, out, N);
        } else {
            // in-place h update (own-rows-only reads precede writes)
            gemmw_kernel<8, true, false><<<gb, 256, 0, stream>>>(
                AGG16, H16, wpi, bl + i * HID, lng + i * HID, lnb + i * HID,
                H16, H16, nullptr, N);
        }
    }
}